// Round 10
// baseline (630.434 us; speedup 1.0000x reference)
//
#include <hip/hip_runtime.h>

#define NNODES 49152
#define NB 4
#define NE 393216
#define MTOT (NB*NNODES)
#define EPS 1e-5f

typedef __attribute__((ext_vector_type(8))) short s8v;   // 8 x bf16 (raw)
typedef __attribute__((ext_vector_type(4))) float f32x4;

__device__ inline float b2f(ushort u){ union{uint i; float f;} v; v.i = ((uint)u)<<16; return v.f; }
__device__ inline ushort f2b(float f){ union{float f; uint i;} v; v.f=f; uint r = v.i + 0x7fff + ((v.i>>16)&1); return (ushort)(r>>16); }

// ---------------- setup kernels ----------------
__global__ __launch_bounds__(256) void k_deg_cnt(const int* __restrict__ row,
    const float* __restrict__ w, float* __restrict__ deg, int* __restrict__ cnt)
{
    int e = blockIdx.x*256 + threadIdx.x;
    if (e >= NE) return;
    int r = row[e];
    atomicAdd(&deg[r], w[e]);
    atomicAdd(&cnt[r], 1);
}

__global__ __launch_bounds__(256) void k_dinv(const float* __restrict__ deg, float* __restrict__ dinv)
{
    int i = blockIdx.x*256 + threadIdx.x;
    if (i >= NNODES) return;
    float d = deg[i];
    dinv[i] = (d > 0.0f) ? rsqrtf(fmaxf(d, EPS)) : 0.0f;
}

__global__ __launch_bounds__(1024) void k_scan(const int* __restrict__ cnt, int* __restrict__ rowptr)
{
    __shared__ int ssum[1024];
    const int CH = NNODES/1024; // 48
    int t = threadIdx.x;
    int base = t*CH;
    int loc[CH];
    int s = 0;
    #pragma unroll
    for (int i = 0; i < CH; ++i) { loc[i] = s; s += cnt[base+i]; }
    ssum[t] = s;
    __syncthreads();
    for (int off = 1; off < 1024; off <<= 1) {
        int v = ssum[t];
        int add = (t >= off) ? ssum[t-off] : 0;
        __syncthreads();
        ssum[t] = v + add;
        __syncthreads();
    }
    int prefix = (t == 0) ? 0 : ssum[t-1];
    #pragma unroll
    for (int i = 0; i < CH; ++i) rowptr[base+i] = prefix + loc[i];
    if (t == 0) rowptr[NNODES] = ssum[1023];
}

__global__ __launch_bounds__(256) void k_fill(const int* __restrict__ row, const int* __restrict__ col,
    const float* __restrict__ w, const float* __restrict__ dinv,
    const int* __restrict__ rowptr, int* __restrict__ fill,
    int* __restrict__ ecol, float* __restrict__ ea)
{
    int e = blockIdx.x*256 + threadIdx.x;
    if (e >= NE) return;
    int r = row[e], c = col[e];
    int pos = rowptr[r] + atomicAdd(&fill[r], 1);
    ecol[pos] = c;
    ea[pos] = w[e] * dinv[r] * dinv[c];
}

// ---------------- pack B into MFMA fragment order (bf16) ----------------
__global__ __launch_bounds__(256) void k_packB(const float* __restrict__ W, int Fin, int NF, int K,
    int mode, ushort* __restrict__ out)
{
    int t = blockIdx.x*256 + threadIdx.x;
    int lane = t & 63;
    int fid = t >> 6;
    if (fid >= (K/32)*NF) return;
    int kb = fid / NF, nb = fid % NF;
    int kbase = kb*32 + ((lane>>4)<<3);
    int n0 = nb*16 + (lane&15);
    #pragma unroll
    for (int j = 0; j < 8; ++j) {
        int kk = kbase + j;
        float v;
        if (mode == 0) {
            if (n0 < 64)       v = W[kk*64 + n0] - W[2*Fin*64 + kk*64 + n0];
            else if (n0 < 128) v = W[Fin*64 + kk*64 + (n0-64)];
            else               v = W[2*Fin*64 + kk*64 + (n0-128)];
        } else {
            v = W[(kk>>6)*64*256 + (kk&63)*256 + n0];
        }
        out[((long)fid*64 + lane)*8 + j] = f2b(v);
    }
}

// ---------------- GEMM1: fp32 x[b*N+n][256] @ Bp1(LDS dbuf) -> 3 bf16 node-major [n*4+b][64] ----------------
__global__ __launch_bounds__(256,3) void k_gemm1(const float* __restrict__ A,
    const ushort* __restrict__ Bp, ushort* __restrict__ C0, ushort* __restrict__ C1, ushort* __restrict__ C2)
{
    __shared__ ushort Bs[2][6144];
    int tid = threadIdx.x;
    int w = tid >> 6, l = tid & 63;
    int lr = l & 15, kg = l >> 4;
    int n0 = blockIdx.x * 16;

    const float* ap = A + ((long)w*NNODES + n0 + lr)*256 + (kg<<3);
    s8v af[8];
    #pragma unroll
    for (int t = 0; t < 8; ++t) {
        float4 v0 = *(const float4*)(ap + t*32);
        float4 v1 = *(const float4*)(ap + t*32 + 4);
        s8v fr;
        fr[0]=(short)f2b(v0.x); fr[1]=(short)f2b(v0.y); fr[2]=(short)f2b(v0.z); fr[3]=(short)f2b(v0.w);
        fr[4]=(short)f2b(v1.x); fr[5]=(short)f2b(v1.y); fr[6]=(short)f2b(v1.z); fr[7]=(short)f2b(v1.w);
        af[t] = fr;
    }
    f32x4 acc[12];
    #pragma unroll
    for (int nb = 0; nb < 12; ++nb) acc[nb] = (f32x4){0.f,0.f,0.f,0.f};

    #pragma unroll
    for (int ps = 0; ps < 3; ++ps) {
        int off = ps*2048 + tid*8;
        *(s8v*)(&Bs[0][off]) = *(const s8v*)(Bp + off);
    }
    #pragma unroll
    for (int t = 0; t < 8; ++t) {
        __syncthreads();
        s8v stg[3];
        if (t < 7) {
            #pragma unroll
            for (int ps = 0; ps < 3; ++ps)
                stg[ps] = *(const s8v*)(Bp + (long)(t+1)*6144 + ps*2048 + tid*8);
        }
        const ushort* bb = &Bs[t&1][l*8];
        #pragma unroll
        for (int nb = 0; nb < 12; ++nb) {
            s8v bfr = *(const s8v*)(bb + nb*512);
            acc[nb] = __builtin_amdgcn_mfma_f32_16x16x32_bf16(af[t], bfr, acc[nb], 0, 0, 0);
        }
        if (t < 7) {
            #pragma unroll
            for (int ps = 0; ps < 3; ++ps)
                *(s8v*)(&Bs[(t+1)&1][ps*2048 + tid*8]) = stg[ps];
        }
    }
    #pragma unroll
    for (int nb = 0; nb < 12; ++nb) {
        ushort* arr = (nb < 4) ? C0 : ((nb < 8) ? C1 : C2);
        int cc = (nb&3)*16 + lr;
        #pragma unroll
        for (int i = 0; i < 4; ++i) {
            long crow = (long)(n0 + kg*4 + i)*4 + w;
            arr[crow*64 + cc] = f2b(acc[nb][i]);
        }
    }
}

// ---------------- GEMM2: norm1(A) node-major [r][64] @ Bp2(LDS) -> 3 bf16 node-major [r][64] ----------------
__global__ __launch_bounds__(256,3) void k_gemm2(const ushort* __restrict__ A,
    const float* __restrict__ nmean, const float* __restrict__ nrs,
    const ushort* __restrict__ Bp, ushort* __restrict__ C0, ushort* __restrict__ C1, ushort* __restrict__ C2)
{
    __shared__ ushort Bs[12288];     // 24 KB
    int tid = threadIdx.x;
    int w = tid >> 6, l = tid & 63;
    int lr = l & 15, kg = l >> 4;
    long rb = (long)blockIdx.x * 64;

    long arow = (rb + w*16 + lr)*64 + (kg<<3);
    s8v raw0 = *(const s8v*)(A + arow);
    s8v raw1 = *(const s8v*)(A + arow + 32);
    #pragma unroll
    for (int ps = 0; ps < 6; ++ps) {
        int off = ps*2048 + tid*8;
        *(s8v*)(&Bs[off]) = *(const s8v*)(Bp + off);
    }
    int b = lr & 3;
    s8v af0, af1;
    #pragma unroll
    for (int j = 0; j < 8; ++j) {
        int c0 = (kg<<3) + j, c1 = 32 + (kg<<3) + j;
        float f0 = fmaxf((b2f((ushort)raw0[j]) - nmean[b*256 + c0]) * nrs[b*256 + c0], 0.f);
        float f1 = fmaxf((b2f((ushort)raw1[j]) - nmean[b*256 + c1]) * nrs[b*256 + c1], 0.f);
        af0[j] = (short)f2b(f0);
        af1[j] = (short)f2b(f1);
    }
    f32x4 acc[12];
    #pragma unroll
    for (int nb = 0; nb < 12; ++nb) acc[nb] = (f32x4){0.f,0.f,0.f,0.f};
    __syncthreads();
    #pragma unroll
    for (int t = 0; t < 2; ++t) {
        const ushort* bb = &Bs[t*6144 + l*8];
        s8v afr = t ? af1 : af0;
        #pragma unroll
        for (int nb = 0; nb < 12; ++nb) {
            s8v bfr = *(const s8v*)(bb + nb*512);
            acc[nb] = __builtin_amdgcn_mfma_f32_16x16x32_bf16(afr, bfr, acc[nb], 0, 0, 0);
        }
    }
    #pragma unroll
    for (int nb = 0; nb < 12; ++nb) {
        ushort* arr = (nb < 4) ? C0 : ((nb < 8) ? C1 : C2);
        int cc = (nb&3)*16 + lr;
        #pragma unroll
        for (int i = 0; i < 4; ++i) {
            long crow = rb + w*16 + kg*4 + i;
            arr[crow*64 + cc] = f2b(acc[nb][i]);
        }
    }
}

// ---------------- GEMM3: 3 bf16 node-major parts (K=192) @ Bp3(LDS dbuf) -> bf16 Ybf[r][256] + fused stats ----------------
__global__ __launch_bounds__(256,3) void k_gemm3(const ushort* __restrict__ A0,
    const ushort* __restrict__ A1, const ushort* __restrict__ A2,
    const ushort* __restrict__ Bp, ushort* __restrict__ C, float* __restrict__ Pst)
{
    __shared__ ushort Bs[2][8192];
    int tid = threadIdx.x;
    int w = tid >> 6, l = tid & 63;
    int lr = l & 15, kg = l >> 4;
    long rb = (long)blockIdx.x * 64;

    long arow = (rb + w*16 + lr)*64 + (kg<<3);
    s8v ap[6];
    ap[0] = *(const s8v*)(A0 + arow); ap[1] = *(const s8v*)(A0 + arow + 32);
    ap[2] = *(const s8v*)(A1 + arow); ap[3] = *(const s8v*)(A1 + arow + 32);
    ap[4] = *(const s8v*)(A2 + arow); ap[5] = *(const s8v*)(A2 + arow + 32);
    f32x4 acc[16];
    #pragma unroll
    for (int nb = 0; nb < 16; ++nb) acc[nb] = (f32x4){0.f,0.f,0.f,0.f};

    #pragma unroll
    for (int ps = 0; ps < 4; ++ps) {
        int off = ps*2048 + tid*8;
        *(s8v*)(&Bs[0][off]) = *(const s8v*)(Bp + off);
    }
    #pragma unroll
    for (int t = 0; t < 6; ++t) {
        __syncthreads();
        s8v stg[4];
        if (t < 5) {
            #pragma unroll
            for (int ps = 0; ps < 4; ++ps)
                stg[ps] = *(const s8v*)(Bp + (long)(t+1)*8192 + ps*2048 + tid*8);
        }
        const ushort* bb = &Bs[t&1][l*8];
        #pragma unroll
        for (int nb = 0; nb < 16; ++nb) {
            s8v bfr = *(const s8v*)(bb + nb*512);
            acc[nb] = __builtin_amdgcn_mfma_f32_16x16x32_bf16(ap[t], bfr, acc[nb], 0, 0, 0);
        }
        if (t < 5) {
            #pragma unroll
            for (int ps = 0; ps < 4; ++ps)
                *(s8v*)(&Bs[(t+1)&1][ps*2048 + tid*8]) = stg[ps];
        }
    }
    #pragma unroll
    for (int nb = 0; nb < 16; ++nb) {
        #pragma unroll
        for (int i = 0; i < 4; ++i) {
            long crow = rb + w*16 + kg*4 + i;
            C[crow*256 + nb*16 + lr] = f2b(acc[nb][i]);
        }
    }
    __syncthreads();
    float* Ls = (float*)Bs;          // [16][256]
    float* Lq = Ls + 4096;
    #pragma unroll
    for (int nb = 0; nb < 16; ++nb) {
        #pragma unroll
        for (int i = 0; i < 4; ++i) {
            float s = acc[nb][i];
            float q = s*s;
            s += __shfl_xor(s, 16); s += __shfl_xor(s, 32);
            q += __shfl_xor(q, 16); q += __shfl_xor(q, 32);
            if (kg == 0) { Ls[(w*4 + i)*256 + nb*16 + lr] = s; Lq[(w*4 + i)*256 + nb*16 + lr] = q; }
        }
    }
    __syncthreads();
    #pragma unroll
    for (int b = 0; b < 4; ++b) {
        float S = Ls[b*256 + tid] + Ls[(4+b)*256 + tid] + Ls[(8+b)*256 + tid] + Ls[(12+b)*256 + tid];
        float Q = Lq[b*256 + tid] + Lq[(4+b)*256 + tid] + Lq[(8+b)*256 + tid] + Lq[(12+b)*256 + tid];
        Pst[(long)blockIdx.x*2048 + b*256 + tid] = S;
        Pst[(long)blockIdx.x*2048 + 1024 + b*256 + tid] = Q;
    }
}

// ---------------- propagation: one full wave per node, 8-deep gather pipeline ----------------
// node row = 512 B; lane covers 8 B (4 bf16). 8 independent 512-B gathers in flight per wave.
__global__ __launch_bounds__(512) void k_prop(
    const int* __restrict__ rowptr, const int* __restrict__ ecol, const float* __restrict__ ea,
    const ushort* __restrict__ src, const ushort* __restrict__ basep, float beta,
    ushort* __restrict__ dst, float alpha, float* __restrict__ Pst)
{
    int g = blockIdx.x*8 + (threadIdx.x >> 6);
    int sub = threadIdx.x & 63;
    int e0 = rowptr[g], e1 = rowptr[g+1];
    float a0 = 0.f, a1 = 0.f, a2 = 0.f, a3 = 0.f;
    int e = e0;
    for (; e + 8 <= e1; e += 8) {
        int cs[8]; float as[8]; ushort4 vs[8];
        #pragma unroll
        for (int k = 0; k < 8; ++k) { cs[k] = ecol[e+k]; as[k] = ea[e+k]; }
        #pragma unroll
        for (int k = 0; k < 8; ++k) vs[k] = *(const ushort4*)(src + (long)cs[k]*256 + sub*4);
        #pragma unroll
        for (int k = 0; k < 8; ++k) {
            a0 += as[k]*b2f(vs[k].x); a1 += as[k]*b2f(vs[k].y);
            a2 += as[k]*b2f(vs[k].z); a3 += as[k]*b2f(vs[k].w);
        }
    }
    if (e + 4 <= e1) {
        int cs[4]; float as[4]; ushort4 vs[4];
        #pragma unroll
        for (int k = 0; k < 4; ++k) { cs[k] = ecol[e+k]; as[k] = ea[e+k]; }
        #pragma unroll
        for (int k = 0; k < 4; ++k) vs[k] = *(const ushort4*)(src + (long)cs[k]*256 + sub*4);
        #pragma unroll
        for (int k = 0; k < 4; ++k) {
            a0 += as[k]*b2f(vs[k].x); a1 += as[k]*b2f(vs[k].y);
            a2 += as[k]*b2f(vs[k].z); a3 += as[k]*b2f(vs[k].w);
        }
        e += 4;
    }
    if (e + 2 <= e1) {
        int c0 = ecol[e], c1 = ecol[e+1];
        float w0 = ea[e], w1 = ea[e+1];
        ushort4 v0 = *(const ushort4*)(src + (long)c0*256 + sub*4);
        ushort4 v1 = *(const ushort4*)(src + (long)c1*256 + sub*4);
        a0 += w0*b2f(v0.x) + w1*b2f(v1.x);
        a1 += w0*b2f(v0.y) + w1*b2f(v1.y);
        a2 += w0*b2f(v0.z) + w1*b2f(v1.z);
        a3 += w0*b2f(v0.w) + w1*b2f(v1.w);
        e += 2;
    }
    if (e < e1) {
        int c = ecol[e]; float w0 = ea[e];
        ushort4 v = *(const ushort4*)(src + (long)c*256 + sub*4);
        a0 += w0*b2f(v.x); a1 += w0*b2f(v.y); a2 += w0*b2f(v.z); a3 += w0*b2f(v.w);
    }
    float o[4];
    o[0] = alpha*a0; o[1] = alpha*a1; o[2] = alpha*a2; o[3] = alpha*a3;
    if (basep) {
        ushort4 bv = *(const ushort4*)(basep + (long)g*256 + sub*4);
        o[0] += beta*b2f(bv.x); o[1] += beta*b2f(bv.y);
        o[2] += beta*b2f(bv.z); o[3] += beta*b2f(bv.w);
    }
    ushort4 ov;
    ov.x = f2b(o[0]); ov.y = f2b(o[1]); ov.z = f2b(o[2]); ov.w = f2b(o[3]);
    *(ushort4*)(dst + (long)g*256 + sub*4) = ov;

    if (Pst) {
        __shared__ float Ls[8][256];
        __shared__ float Lq[8][256];
        int grp = threadIdx.x >> 6;
        #pragma unroll
        for (int j = 0; j < 4; ++j) {
            Ls[grp][sub*4 + j] = o[j];
            Lq[grp][sub*4 + j] = o[j]*o[j];
        }
        __syncthreads();
        int t = threadIdx.x;
        if (t < 256) {
            float s = 0.f, q = 0.f;
            #pragma unroll
            for (int k = 0; k < 8; ++k) { s += Ls[k][t]; q += Lq[k][t]; }
            Pst[(long)blockIdx.x*512 + t] = s;
            Pst[(long)blockIdx.x*512 + 256 + t] = q;
        }
    }
}

// ---------------- tree reduction (atomic-free, 3-level, high parallelism) ----------------
__global__ __launch_bounds__(256) void k_redgen(const float* __restrict__ in, float* __restrict__ out,
    int S, int nin)
{
    int j = blockIdx.x*256 + threadIdx.x;
    int o = blockIdx.y;
    long base = (long)o*nin*S + j;
    float s = 0.f;
    for (int k = 0; k < nin; ++k) s += in[base + (long)k*S];
    out[(long)o*S + j] = s;
}

__global__ __launch_bounds__(256) void k_redfin(const float* __restrict__ in, int S, int nin, int Cw,
    float* __restrict__ mean, float* __restrict__ rs)
{
    int half = S >> 1;
    int j = blockIdx.x*256 + threadIdx.x;
    if (j >= half) return;
    float s = 0.f, q = 0.f;
    for (int k = 0; k < nin; ++k) {
        s += in[(long)k*S + j];
        q += in[(long)k*S + half + j];
    }
    float m = s / (float)NNODES;
    float v = q / (float)NNODES - m*m;
    int b = j / Cw, c = j - b*Cw;
    mean[b*256 + c] = m;
    rs[b*256 + c] = rsqrtf(v + EPS);
}

// ---------------- norm-relu (node-major [MTOT*64] bf16) ----------------
__global__ __launch_bounds__(256) void k_normrelu(const ushort* __restrict__ y,
    const float* __restrict__ mean, const float* __restrict__ rs, ushort* __restrict__ X)
{
    int t = threadIdx.x;
    long e = (long)blockIdx.x*2048 + t*8;
    int b = (t>>3)&3, c0 = (t&7)*8;
    s8v v = *(const s8v*)(y + e);
    float4 m0 = *(const float4*)(mean + b*256 + c0);
    float4 m1 = *(const float4*)(mean + b*256 + c0 + 4);
    float4 r0 = *(const float4*)(rs + b*256 + c0);
    float4 r1 = *(const float4*)(rs + b*256 + c0 + 4);
    float mm[8] = {m0.x,m0.y,m0.z,m0.w,m1.x,m1.y,m1.z,m1.w};
    float rr[8] = {r0.x,r0.y,r0.z,r0.w,r1.x,r1.y,r1.z,r1.w};
    s8v o;
    #pragma unroll
    for (int j = 0; j < 8; ++j) o[j] = (short)f2b(fmaxf((b2f((ushort)v[j]) - mm[j])*rr[j], 0.f));
    *(s8v*)(X + e) = o;
}

// ---------------- final: out[(b*N+n)*256+c] = relu((Ybf[(n*4+b)*256+c]-mean)*rs) + x ----------------
__global__ __launch_bounds__(256) void k_final(const ushort* __restrict__ Ybf,
    const float* __restrict__ x, const float* __restrict__ mean, const float* __restrict__ rs,
    float* __restrict__ out)
{
    int t = threadIdx.x;
    long orow = (long)blockIdx.x*8 + (t>>5);
    int c0 = (t&31)*8;
    int b = (int)(orow / NNODES);
    int n = (int)(orow - (long)b*NNODES);
    s8v v = *(const s8v*)(Ybf + ((long)n*4 + b)*256 + c0);
    float4 m0 = *(const float4*)(mean + b*256 + c0);
    float4 m1 = *(const float4*)(mean + b*256 + c0 + 4);
    float4 r0 = *(const float4*)(rs + b*256 + c0);
    float4 r1 = *(const float4*)(rs + b*256 + c0 + 4);
    float mm[8] = {m0.x,m0.y,m0.z,m0.w,m1.x,m1.y,m1.z,m1.w};
    float rr[8] = {r0.x,r0.y,r0.z,r0.w,r1.x,r1.y,r1.z,r1.w};
    const float* xp = x + orow*256 + c0;
    float* op = out + orow*256 + c0;
    #pragma unroll
    for (int j = 0; j < 8; ++j)
        op[j] = fmaxf((b2f((ushort)v[j]) - mm[j])*rr[j], 0.f) + xp[j];
}

extern "C" void kernel_launch(void* const* d_in, const int* in_sizes, int n_in,
                              void* d_out, int out_size, void* d_ws, size_t ws_size,
                              hipStream_t stream)
{
    const float* x  = (const float*)d_in[0];
    const int*   ei = (const int*)d_in[1];
    const float* ew = (const float*)d_in[2];
    const float* W1 = (const float*)d_in[3];
    const float* W2 = (const float*)d_in[5];
    const float* W3 = (const float*)d_in[7];
    const int* row = ei;
    const int* col = ei + NE;

    char* p = (char*)d_ws;
    size_t used = 0;
    auto alloc = [&](size_t bytes) -> void* {
        void* r = p + used;
        used += (bytes + 1023) & ~(size_t)1023;
        return r;
    };
    float* deg   = (float*)alloc((size_t)3*NNODES*4);     // deg | cnt | fill (zeroed)
    int*   cnt   = (int*)(deg + NNODES);
    int*   fillc = (int*)(deg + 2*NNODES);
    float* dinv  = (float*)alloc((size_t)NNODES*4);
    int*   rowptr= (int*)alloc((size_t)(NNODES+1)*4);
    int*   ecol  = (int*)alloc((size_t)NE*4);
    float* ea    = (float*)alloc((size_t)NE*4);
    float* mrs   = (float*)alloc((size_t)3*2*1024*4);     // per layer: mean[1024] | rs[1024]
    ushort* Bp1  = (ushort*)alloc((size_t)256*192*2);
    ushort* Bp2  = (ushort*)alloc((size_t)64*192*2);
    ushort* Bp3  = (ushort*)alloc((size_t)192*256*2);
    ushort* Za   = (ushort*)alloc((size_t)MTOT*64*2);
    ushort* Zb   = (ushort*)alloc((size_t)MTOT*64*2);
    ushort* Zc   = (ushort*)alloc((size_t)MTOT*64*2);
    ushort* Zd   = (ushort*)alloc((size_t)MTOT*64*2);
    float* Pbig  = (float*)alloc((size_t)6144*512*4);     // prop stats partials (12.6 MB)
    float* PPa   = (float*)alloc((size_t)256*2048*4);     // 2 MB
    float* PPb   = (float*)alloc((size_t)16*2048*4);      // 128 KB
    ushort* Ybf  = (ushort*)alloc((size_t)MTOT*256*2);    // 100 MB
    if (ws_size < used) return;

    float* mean1 = mrs;          float* rs1 = mrs + 1024;
    float* mean2 = mrs + 2048;   float* rs2 = mrs + 3072;
    float* mean3 = mrs + 4096;   float* rs3 = mrs + 5120;
    float* Pst3  = (float*)d_out;   // gemm3 stats partials (3072x2048 fp32 = 25 MB < 201 MB),
                                    // consumed by reductions BEFORE k_final overwrites d_out

    // ---- setup ----
    hipMemsetAsync(deg, 0, (size_t)3*NNODES*4, stream);
    k_deg_cnt<<<NE/256, 256, 0, stream>>>(row, ew, deg, cnt);
    k_dinv<<<NNODES/256, 256, 0, stream>>>(deg, dinv);
    k_scan<<<1, 1024, 0, stream>>>(cnt, rowptr);
    k_fill<<<NE/256, 256, 0, stream>>>(row, col, ew, dinv, rowptr, fillc, ecol, ea);
    k_packB<<<24, 256, 0, stream>>>(W1, 256, 12, 256, 0, Bp1);
    k_packB<<<6, 256, 0, stream>>>(W2, 64, 12, 64, 0, Bp2);
    k_packB<<<24, 256, 0, stream>>>(W3, 64, 16, 192, 1, Bp3);

    // ---- layer 1: 256 -> 64 (Za=y0, Zb=u1, Zc=u2, node-major) ----
    k_gemm1<<<NNODES/16, 256, 0, stream>>>(x, Bp1, Za, Zb, Zc);
    k_prop<<<NNODES/8, 512, 0, stream>>>(rowptr, ecol, ea, Zc, Zb, 1.f, Zb, -2.f, nullptr);   // z = u1 - 2S(u2)
    k_prop<<<NNODES/8, 512, 0, stream>>>(rowptr, ecol, ea, Zb, Za, 1.f, Za, -1.f, Pbig);      // y1 = y0 - S(z) + stats
    k_redgen<<<dim3(2,512), 256, 0, stream>>>(Pbig, PPa, 512, 12);
    k_redgen<<<dim3(2,32), 256, 0, stream>>>(PPa, PPb, 512, 16);
    k_redfin<<<1, 256, 0, stream>>>(PPb, 512, 32, 64, mean1, rs1);
    // y1 (pre-norm) stays in Za; norm1 fused into gemm2

    // ---- layer 2: 64 -> 64 ----
    k_gemm2<<<MTOT/64, 256, 0, stream>>>(Za, mean1, rs1, Bp2, Zb, Zc, Zd);
    k_prop<<<NNODES/8, 512, 0, stream>>>(rowptr, ecol, ea, Zd, Zc, 1.f, Zc, -2.f, nullptr);
    k_prop<<<NNODES/8, 512, 0, stream>>>(rowptr, ecol, ea, Zc, Zb, 1.f, Zb, -1.f, Pbig);      // y2 + stats
    k_redgen<<<dim3(2,512), 256, 0, stream>>>(Pbig, PPa, 512, 12);
    k_redgen<<<dim3(2,32), 256, 0, stream>>>(PPa, PPb, 512, 16);
    k_redfin<<<1, 256, 0, stream>>>(PPb, 512, 32, 64, mean2, rs2);
    k_normrelu<<<MTOT*64/2048, 256, 0, stream>>>(Zb, mean2, rs2, Za);                          // X3 = Za

    // ---- layer 3: 64 -> 256 (propagate in 64-dim input space) ----
    k_prop<<<NNODES/8, 512, 0, stream>>>(rowptr, ecol, ea, Za, (const ushort*)nullptr, 0.f, Zb, -1.f, nullptr); // T1 = -S(X3)
    k_prop<<<NNODES/8, 512, 0, stream>>>(rowptr, ecol, ea, Zb, Za, -1.f, Zc, -2.f, nullptr);                    // T2 = -X3 - 2S(T1)
    k_gemm3<<<MTOT/64, 256, 0, stream>>>(Za, Zb, Zc, Bp3, Ybf, Pst3);
    k_redgen<<<dim3(8,256), 256, 0, stream>>>(Pst3, PPa, 2048, 12);
    k_redgen<<<dim3(8,16), 256, 0, stream>>>(PPa, PPb, 2048, 16);
    k_redfin<<<4, 256, 0, stream>>>(PPb, 2048, 16, 256, mean3, rs3);
    k_final<<<MTOT/8, 256, 0, stream>>>(Ybf, x, mean3, rs3, (float*)d_out);
}

// Round 11
// 616.030 us; speedup vs baseline: 1.0234x; 1.0234x over previous
//
#include <hip/hip_runtime.h>

#define NNODES 49152
#define NB 4
#define NE 393216
#define MTOT (NB*NNODES)
#define EPS 1e-5f

typedef __attribute__((ext_vector_type(8))) short s8v;   // 8 x bf16 (raw)
typedef __attribute__((ext_vector_type(4))) float f32x4;

__device__ inline float b2f(ushort u){ union{uint i; float f;} v; v.i = ((uint)u)<<16; return v.f; }
__device__ inline ushort f2b(float f){ union{float f; uint i;} v; v.f=f; uint r = v.i + 0x7fff + ((v.i>>16)&1); return (ushort)(r>>16); }

// ---------------- setup kernels ----------------
__global__ __launch_bounds__(256) void k_deg_cnt(const int* __restrict__ row,
    const float* __restrict__ w, float* __restrict__ deg, int* __restrict__ cnt)
{
    int e = blockIdx.x*256 + threadIdx.x;
    if (e >= NE) return;
    int r = row[e];
    atomicAdd(&deg[r], w[e]);
    atomicAdd(&cnt[r], 1);
}

__global__ __launch_bounds__(256) void k_dinv(const float* __restrict__ deg, float* __restrict__ dinv)
{
    int i = blockIdx.x*256 + threadIdx.x;
    if (i >= NNODES) return;
    float d = deg[i];
    dinv[i] = (d > 0.0f) ? rsqrtf(fmaxf(d, EPS)) : 0.0f;
}

__global__ __launch_bounds__(1024) void k_scan(const int* __restrict__ cnt, int* __restrict__ rowptr)
{
    __shared__ int ssum[1024];
    const int CH = NNODES/1024; // 48
    int t = threadIdx.x;
    int base = t*CH;
    int loc[CH];
    int s = 0;
    #pragma unroll
    for (int i = 0; i < CH; ++i) { loc[i] = s; s += cnt[base+i]; }
    ssum[t] = s;
    __syncthreads();
    for (int off = 1; off < 1024; off <<= 1) {
        int v = ssum[t];
        int add = (t >= off) ? ssum[t-off] : 0;
        __syncthreads();
        ssum[t] = v + add;
        __syncthreads();
    }
    int prefix = (t == 0) ? 0 : ssum[t-1];
    #pragma unroll
    for (int i = 0; i < CH; ++i) rowptr[base+i] = prefix + loc[i];
    if (t == 0) rowptr[NNODES] = ssum[1023];
}

// build packed edge records: epk[pos] = {col, weight-bits}
__global__ __launch_bounds__(256) void k_fill(const int* __restrict__ row, const int* __restrict__ col,
    const float* __restrict__ w, const float* __restrict__ dinv,
    const int* __restrict__ rowptr, int* __restrict__ fill, int2* __restrict__ epk)
{
    int e = blockIdx.x*256 + threadIdx.x;
    if (e >= NE) return;
    int r = row[e], c = col[e];
    int pos = rowptr[r] + atomicAdd(&fill[r], 1);
    float a = w[e] * dinv[r] * dinv[c];
    int2 pk; pk.x = c; pk.y = __float_as_int(a);
    epk[pos] = pk;
}

// ---------------- pack B into MFMA fragment order (bf16) ----------------
__global__ __launch_bounds__(256) void k_packB(const float* __restrict__ W, int Fin, int NF, int K,
    int mode, ushort* __restrict__ out)
{
    int t = blockIdx.x*256 + threadIdx.x;
    int lane = t & 63;
    int fid = t >> 6;
    if (fid >= (K/32)*NF) return;
    int kb = fid / NF, nb = fid % NF;
    int kbase = kb*32 + ((lane>>4)<<3);
    int n0 = nb*16 + (lane&15);
    #pragma unroll
    for (int j = 0; j < 8; ++j) {
        int kk = kbase + j;
        float v;
        if (mode == 0) {
            if (n0 < 64)       v = W[kk*64 + n0] - W[2*Fin*64 + kk*64 + n0];
            else if (n0 < 128) v = W[Fin*64 + kk*64 + (n0-64)];
            else               v = W[2*Fin*64 + kk*64 + (n0-128)];
        } else {
            v = W[(kk>>6)*64*256 + (kk&63)*256 + n0];
        }
        out[((long)fid*64 + lane)*8 + j] = f2b(v);
    }
}

// ---------------- GEMM1: fp32 x[b*N+n][256] @ Bp1(LDS dbuf) -> 3 bf16 node-major [n*4+b][64] ----------------
__global__ __launch_bounds__(256,3) void k_gemm1(const float* __restrict__ A,
    const ushort* __restrict__ Bp, ushort* __restrict__ C0, ushort* __restrict__ C1, ushort* __restrict__ C2)
{
    __shared__ ushort Bs[2][6144];
    int tid = threadIdx.x;
    int w = tid >> 6, l = tid & 63;
    int lr = l & 15, kg = l >> 4;
    int n0 = blockIdx.x * 16;

    const float* ap = A + ((long)w*NNODES + n0 + lr)*256 + (kg<<3);
    s8v af[8];
    #pragma unroll
    for (int t = 0; t < 8; ++t) {
        float4 v0 = *(const float4*)(ap + t*32);
        float4 v1 = *(const float4*)(ap + t*32 + 4);
        s8v fr;
        fr[0]=(short)f2b(v0.x); fr[1]=(short)f2b(v0.y); fr[2]=(short)f2b(v0.z); fr[3]=(short)f2b(v0.w);
        fr[4]=(short)f2b(v1.x); fr[5]=(short)f2b(v1.y); fr[6]=(short)f2b(v1.z); fr[7]=(short)f2b(v1.w);
        af[t] = fr;
    }
    f32x4 acc[12];
    #pragma unroll
    for (int nb = 0; nb < 12; ++nb) acc[nb] = (f32x4){0.f,0.f,0.f,0.f};

    #pragma unroll
    for (int ps = 0; ps < 3; ++ps) {
        int off = ps*2048 + tid*8;
        *(s8v*)(&Bs[0][off]) = *(const s8v*)(Bp + off);
    }
    #pragma unroll
    for (int t = 0; t < 8; ++t) {
        __syncthreads();
        s8v stg[3];
        if (t < 7) {
            #pragma unroll
            for (int ps = 0; ps < 3; ++ps)
                stg[ps] = *(const s8v*)(Bp + (long)(t+1)*6144 + ps*2048 + tid*8);
        }
        const ushort* bb = &Bs[t&1][l*8];
        #pragma unroll
        for (int nb = 0; nb < 12; ++nb) {
            s8v bfr = *(const s8v*)(bb + nb*512);
            acc[nb] = __builtin_amdgcn_mfma_f32_16x16x32_bf16(af[t], bfr, acc[nb], 0, 0, 0);
        }
        if (t < 7) {
            #pragma unroll
            for (int ps = 0; ps < 3; ++ps)
                *(s8v*)(&Bs[(t+1)&1][ps*2048 + tid*8]) = stg[ps];
        }
    }
    #pragma unroll
    for (int nb = 0; nb < 12; ++nb) {
        ushort* arr = (nb < 4) ? C0 : ((nb < 8) ? C1 : C2);
        int cc = (nb&3)*16 + lr;
        #pragma unroll
        for (int i = 0; i < 4; ++i) {
            long crow = (long)(n0 + kg*4 + i)*4 + w;
            arr[crow*64 + cc] = f2b(acc[nb][i]);
        }
    }
}

// ---------------- GEMM2: norm1(A) node-major [r][64] @ Bp2(LDS) -> 3 bf16 node-major [r][64] ----------------
__global__ __launch_bounds__(256,3) void k_gemm2(const ushort* __restrict__ A,
    const float* __restrict__ nmean, const float* __restrict__ nrs,
    const ushort* __restrict__ Bp, ushort* __restrict__ C0, ushort* __restrict__ C1, ushort* __restrict__ C2)
{
    __shared__ ushort Bs[12288];     // 24 KB
    int tid = threadIdx.x;
    int w = tid >> 6, l = tid & 63;
    int lr = l & 15, kg = l >> 4;
    long rb = (long)blockIdx.x * 64;

    long arow = (rb + w*16 + lr)*64 + (kg<<3);
    s8v raw0 = *(const s8v*)(A + arow);
    s8v raw1 = *(const s8v*)(A + arow + 32);
    #pragma unroll
    for (int ps = 0; ps < 6; ++ps) {
        int off = ps*2048 + tid*8;
        *(s8v*)(&Bs[off]) = *(const s8v*)(Bp + off);
    }
    int b = lr & 3;
    s8v af0, af1;
    #pragma unroll
    for (int j = 0; j < 8; ++j) {
        int c0 = (kg<<3) + j, c1 = 32 + (kg<<3) + j;
        float f0 = fmaxf((b2f((ushort)raw0[j]) - nmean[b*256 + c0]) * nrs[b*256 + c0], 0.f);
        float f1 = fmaxf((b2f((ushort)raw1[j]) - nmean[b*256 + c1]) * nrs[b*256 + c1], 0.f);
        af0[j] = (short)f2b(f0);
        af1[j] = (short)f2b(f1);
    }
    f32x4 acc[12];
    #pragma unroll
    for (int nb = 0; nb < 12; ++nb) acc[nb] = (f32x4){0.f,0.f,0.f,0.f};
    __syncthreads();
    #pragma unroll
    for (int t = 0; t < 2; ++t) {
        const ushort* bb = &Bs[t*6144 + l*8];
        s8v afr = t ? af1 : af0;
        #pragma unroll
        for (int nb = 0; nb < 12; ++nb) {
            s8v bfr = *(const s8v*)(bb + nb*512);
            acc[nb] = __builtin_amdgcn_mfma_f32_16x16x32_bf16(afr, bfr, acc[nb], 0, 0, 0);
        }
    }
    #pragma unroll
    for (int nb = 0; nb < 12; ++nb) {
        ushort* arr = (nb < 4) ? C0 : ((nb < 8) ? C1 : C2);
        int cc = (nb&3)*16 + lr;
        #pragma unroll
        for (int i = 0; i < 4; ++i) {
            long crow = rb + w*16 + kg*4 + i;
            arr[crow*64 + cc] = f2b(acc[nb][i]);
        }
    }
}

// ---------------- GEMM3: 3 bf16 node-major parts (K=192) @ Bp3(LDS dbuf) -> bf16 Ybf[r][256] + fused stats ----------------
__global__ __launch_bounds__(256,3) void k_gemm3(const ushort* __restrict__ A0,
    const ushort* __restrict__ A1, const ushort* __restrict__ A2,
    const ushort* __restrict__ Bp, ushort* __restrict__ C, float* __restrict__ Pst)
{
    __shared__ ushort Bs[2][8192];
    int tid = threadIdx.x;
    int w = tid >> 6, l = tid & 63;
    int lr = l & 15, kg = l >> 4;
    long rb = (long)blockIdx.x * 64;

    long arow = (rb + w*16 + lr)*64 + (kg<<3);
    s8v ap[6];
    ap[0] = *(const s8v*)(A0 + arow); ap[1] = *(const s8v*)(A0 + arow + 32);
    ap[2] = *(const s8v*)(A1 + arow); ap[3] = *(const s8v*)(A1 + arow + 32);
    ap[4] = *(const s8v*)(A2 + arow); ap[5] = *(const s8v*)(A2 + arow + 32);
    f32x4 acc[16];
    #pragma unroll
    for (int nb = 0; nb < 16; ++nb) acc[nb] = (f32x4){0.f,0.f,0.f,0.f};

    #pragma unroll
    for (int ps = 0; ps < 4; ++ps) {
        int off = ps*2048 + tid*8;
        *(s8v*)(&Bs[0][off]) = *(const s8v*)(Bp + off);
    }
    #pragma unroll
    for (int t = 0; t < 6; ++t) {
        __syncthreads();
        s8v stg[4];
        if (t < 5) {
            #pragma unroll
            for (int ps = 0; ps < 4; ++ps)
                stg[ps] = *(const s8v*)(Bp + (long)(t+1)*8192 + ps*2048 + tid*8);
        }
        const ushort* bb = &Bs[t&1][l*8];
        #pragma unroll
        for (int nb = 0; nb < 16; ++nb) {
            s8v bfr = *(const s8v*)(bb + nb*512);
            acc[nb] = __builtin_amdgcn_mfma_f32_16x16x32_bf16(ap[t], bfr, acc[nb], 0, 0, 0);
        }
        if (t < 5) {
            #pragma unroll
            for (int ps = 0; ps < 4; ++ps)
                *(s8v*)(&Bs[(t+1)&1][ps*2048 + tid*8]) = stg[ps];
        }
    }
    #pragma unroll
    for (int nb = 0; nb < 16; ++nb) {
        #pragma unroll
        for (int i = 0; i < 4; ++i) {
            long crow = rb + w*16 + kg*4 + i;
            C[crow*256 + nb*16 + lr] = f2b(acc[nb][i]);
        }
    }
    __syncthreads();
    float* Ls = (float*)Bs;          // [16][256]
    float* Lq = Ls + 4096;
    #pragma unroll
    for (int nb = 0; nb < 16; ++nb) {
        #pragma unroll
        for (int i = 0; i < 4; ++i) {
            float s = acc[nb][i];
            float q = s*s;
            s += __shfl_xor(s, 16); s += __shfl_xor(s, 32);
            q += __shfl_xor(q, 16); q += __shfl_xor(q, 32);
            if (kg == 0) { Ls[(w*4 + i)*256 + nb*16 + lr] = s; Lq[(w*4 + i)*256 + nb*16 + lr] = q; }
        }
    }
    __syncthreads();
    #pragma unroll
    for (int b = 0; b < 4; ++b) {
        float S = Ls[b*256 + tid] + Ls[(4+b)*256 + tid] + Ls[(8+b)*256 + tid] + Ls[(12+b)*256 + tid];
        float Q = Lq[b*256 + tid] + Lq[(4+b)*256 + tid] + Lq[(8+b)*256 + tid] + Lq[(12+b)*256 + tid];
        Pst[(long)blockIdx.x*2048 + b*256 + tid] = S;
        Pst[(long)blockIdx.x*2048 + 1024 + b*256 + tid] = Q;
    }
}

// ---------------- propagation (CSR gather, node-major bf16, 4-deep pipelined, packed edges) ----------------
__global__ __launch_bounds__(256) void k_prop(
    const int* __restrict__ rowptr, const int2* __restrict__ epk,
    const ushort* __restrict__ src, const ushort* __restrict__ basep, float beta,
    ushort* __restrict__ dst, float alpha, float* __restrict__ Pst)
{
    int g = blockIdx.x*8 + (threadIdx.x >> 5);
    int sub = threadIdx.x & 31;
    int e0 = rowptr[g], e1 = rowptr[g+1];
    float acc[8];
    #pragma unroll
    for (int j = 0; j < 8; ++j) acc[j] = 0.f;
    int e = e0;
    for (; e + 4 <= e1; e += 4) {
        int2 p0 = epk[e], p1 = epk[e+1], p2 = epk[e+2], p3 = epk[e+3];
        float a0 = __int_as_float(p0.y), a1 = __int_as_float(p1.y);
        float a2 = __int_as_float(p2.y), a3 = __int_as_float(p3.y);
        s8v v0 = *(const s8v*)(src + (long)p0.x*256 + sub*8);
        s8v v1 = *(const s8v*)(src + (long)p1.x*256 + sub*8);
        s8v v2 = *(const s8v*)(src + (long)p2.x*256 + sub*8);
        s8v v3 = *(const s8v*)(src + (long)p3.x*256 + sub*8);
        #pragma unroll
        for (int j = 0; j < 8; ++j)
            acc[j] += a0*b2f((ushort)v0[j]) + a1*b2f((ushort)v1[j])
                    + a2*b2f((ushort)v2[j]) + a3*b2f((ushort)v3[j]);
    }
    for (; e < e1; ++e) {
        int2 pk = epk[e];
        float a = __int_as_float(pk.y);
        s8v v = *(const s8v*)(src + (long)pk.x*256 + sub*8);
        #pragma unroll
        for (int j = 0; j < 8; ++j) acc[j] += a*b2f((ushort)v[j]);
    }
    float o[8];
    if (basep) {
        s8v bv = *(const s8v*)(basep + (long)g*256 + sub*8);
        #pragma unroll
        for (int j = 0; j < 8; ++j) o[j] = alpha*acc[j] + beta*b2f((ushort)bv[j]);
    } else {
        #pragma unroll
        for (int j = 0; j < 8; ++j) o[j] = alpha*acc[j];
    }
    s8v ov;
    #pragma unroll
    for (int j = 0; j < 8; ++j) ov[j] = (short)f2b(o[j]);
    *(s8v*)(dst + (long)g*256 + sub*8) = ov;

    if (Pst) {
        __shared__ float Ls[8][256];
        __shared__ float Lq[8][256];
        int grp = threadIdx.x >> 5;
        #pragma unroll
        for (int j = 0; j < 8; ++j) {
            Ls[grp][sub*8 + j] = o[j];
            Lq[grp][sub*8 + j] = o[j]*o[j];
        }
        __syncthreads();
        int t = threadIdx.x;
        float s = 0.f, q = 0.f;
        #pragma unroll
        for (int k = 0; k < 8; ++k) { s += Ls[k][t]; q += Lq[k][t]; }
        Pst[(long)blockIdx.x*512 + t] = s;
        Pst[(long)blockIdx.x*512 + 256 + t] = q;
    }
}

// ---------------- tree reduction (atomic-free, 3-level, high parallelism) ----------------
__global__ __launch_bounds__(256) void k_redgen(const float* __restrict__ in, float* __restrict__ out,
    int S, int nin)
{
    int j = blockIdx.x*256 + threadIdx.x;
    int o = blockIdx.y;
    long base = (long)o*nin*S + j;
    float s = 0.f;
    for (int k = 0; k < nin; ++k) s += in[base + (long)k*S];
    out[(long)o*S + j] = s;
}

__global__ __launch_bounds__(256) void k_redfin(const float* __restrict__ in, int S, int nin, int Cw,
    float* __restrict__ mean, float* __restrict__ rs)
{
    int half = S >> 1;
    int j = blockIdx.x*256 + threadIdx.x;
    if (j >= half) return;
    float s = 0.f, q = 0.f;
    for (int k = 0; k < nin; ++k) {
        s += in[(long)k*S + j];
        q += in[(long)k*S + half + j];
    }
    float m = s / (float)NNODES;
    float v = q / (float)NNODES - m*m;
    int b = j / Cw, c = j - b*Cw;
    mean[b*256 + c] = m;
    rs[b*256 + c] = rsqrtf(v + EPS);
}

// ---------------- norm-relu (node-major [MTOT*64] bf16) ----------------
__global__ __launch_bounds__(256) void k_normrelu(const ushort* __restrict__ y,
    const float* __restrict__ mean, const float* __restrict__ rs, ushort* __restrict__ X)
{
    int t = threadIdx.x;
    long e = (long)blockIdx.x*2048 + t*8;
    int b = (t>>3)&3, c0 = (t&7)*8;
    s8v v = *(const s8v*)(y + e);
    float4 m0 = *(const float4*)(mean + b*256 + c0);
    float4 m1 = *(const float4*)(mean + b*256 + c0 + 4);
    float4 r0 = *(const float4*)(rs + b*256 + c0);
    float4 r1 = *(const float4*)(rs + b*256 + c0 + 4);
    float mm[8] = {m0.x,m0.y,m0.z,m0.w,m1.x,m1.y,m1.z,m1.w};
    float rr[8] = {r0.x,r0.y,r0.z,r0.w,r1.x,r1.y,r1.z,r1.w};
    s8v o;
    #pragma unroll
    for (int j = 0; j < 8; ++j) o[j] = (short)f2b(fmaxf((b2f((ushort)v[j]) - mm[j])*rr[j], 0.f));
    *(s8v*)(X + e) = o;
}

// ---------------- final: out[(b*N+n)*256+c] = relu((Ybf[(n*4+b)*256+c]-mean)*rs) + x ----------------
__global__ __launch_bounds__(256) void k_final(const ushort* __restrict__ Ybf,
    const float* __restrict__ x, const float* __restrict__ mean, const float* __restrict__ rs,
    float* __restrict__ out)
{
    int t = threadIdx.x;
    long orow = (long)blockIdx.x*8 + (t>>5);
    int c0 = (t&31)*8;
    int b = (int)(orow / NNODES);
    int n = (int)(orow - (long)b*NNODES);
    s8v v = *(const s8v*)(Ybf + ((long)n*4 + b)*256 + c0);
    float4 m0 = *(const float4*)(mean + b*256 + c0);
    float4 m1 = *(const float4*)(mean + b*256 + c0 + 4);
    float4 r0 = *(const float4*)(rs + b*256 + c0);
    float4 r1 = *(const float4*)(rs + b*256 + c0 + 4);
    float mm[8] = {m0.x,m0.y,m0.z,m0.w,m1.x,m1.y,m1.z,m1.w};
    float rr[8] = {r0.x,r0.y,r0.z,r0.w,r1.x,r1.y,r1.z,r1.w};
    const float* xp = x + orow*256 + c0;
    float* op = out + orow*256 + c0;
    #pragma unroll
    for (int j = 0; j < 8; ++j)
        op[j] = fmaxf((b2f((ushort)v[j]) - mm[j])*rr[j], 0.f) + xp[j];
}

extern "C" void kernel_launch(void* const* d_in, const int* in_sizes, int n_in,
                              void* d_out, int out_size, void* d_ws, size_t ws_size,
                              hipStream_t stream)
{
    const float* x  = (const float*)d_in[0];
    const int*   ei = (const int*)d_in[1];
    const float* ew = (const float*)d_in[2];
    const float* W1 = (const float*)d_in[3];
    const float* W2 = (const float*)d_in[5];
    const float* W3 = (const float*)d_in[7];
    const int* row = ei;
    const int* col = ei + NE;

    char* p = (char*)d_ws;
    size_t used = 0;
    auto alloc = [&](size_t bytes) -> void* {
        void* r = p + used;
        used += (bytes + 1023) & ~(size_t)1023;
        return r;
    };
    float* deg   = (float*)alloc((size_t)3*NNODES*4);     // deg | cnt | fill (zeroed)
    int*   cnt   = (int*)(deg + NNODES);
    int*   fillc = (int*)(deg + 2*NNODES);
    float* dinv  = (float*)alloc((size_t)NNODES*4);
    int*   rowptr= (int*)alloc((size_t)(NNODES+1)*4);
    int2*  epk   = (int2*)alloc((size_t)NE*8);
    float* mrs   = (float*)alloc((size_t)3*2*1024*4);     // per layer: mean[1024] | rs[1024]
    ushort* Bp1  = (ushort*)alloc((size_t)256*192*2);
    ushort* Bp2  = (ushort*)alloc((size_t)64*192*2);
    ushort* Bp3  = (ushort*)alloc((size_t)192*256*2);
    ushort* Za   = (ushort*)alloc((size_t)MTOT*64*2);
    ushort* Zb   = (ushort*)alloc((size_t)MTOT*64*2);
    ushort* Zc   = (ushort*)alloc((size_t)MTOT*64*2);
    ushort* Zd   = (ushort*)alloc((size_t)MTOT*64*2);
    float* Pbig  = (float*)alloc((size_t)6144*512*4);     // prop stats partials (12.6 MB)
    float* PPa   = (float*)alloc((size_t)256*2048*4);     // 2 MB
    float* PPb   = (float*)alloc((size_t)16*2048*4);      // 128 KB
    ushort* Ybf  = (ushort*)alloc((size_t)MTOT*256*2);    // 100 MB
    if (ws_size < used) return;

    float* mean1 = mrs;          float* rs1 = mrs + 1024;
    float* mean2 = mrs + 2048;   float* rs2 = mrs + 3072;
    float* mean3 = mrs + 4096;   float* rs3 = mrs + 5120;
    float* Pst3  = (float*)d_out;   // gemm3 stats partials (3072x2048 fp32 = 25 MB < 201 MB),
                                    // consumed by reductions BEFORE k_final overwrites d_out

    // ---- setup ----
    hipMemsetAsync(deg, 0, (size_t)3*NNODES*4, stream);
    k_deg_cnt<<<NE/256, 256, 0, stream>>>(row, ew, deg, cnt);
    k_dinv<<<NNODES/256, 256, 0, stream>>>(deg, dinv);
    k_scan<<<1, 1024, 0, stream>>>(cnt, rowptr);
    k_fill<<<NE/256, 256, 0, stream>>>(row, col, ew, dinv, rowptr, fillc, epk);
    k_packB<<<24, 256, 0, stream>>>(W1, 256, 12, 256, 0, Bp1);
    k_packB<<<6, 256, 0, stream>>>(W2, 64, 12, 64, 0, Bp2);
    k_packB<<<24, 256, 0, stream>>>(W3, 64, 16, 192, 1, Bp3);

    // ---- layer 1: 256 -> 64 (Za=y0, Zb=u1, Zc=u2, node-major) ----
    k_gemm1<<<NNODES/16, 256, 0, stream>>>(x, Bp1, Za, Zb, Zc);
    k_prop<<<NNODES/8, 256, 0, stream>>>(rowptr, epk, Zc, Zb, 1.f, Zb, -2.f, nullptr);   // z = u1 - 2S(u2)
    k_prop<<<NNODES/8, 256, 0, stream>>>(rowptr, epk, Zb, Za, 1.f, Za, -1.f, Pbig);      // y1 = y0 - S(z) + stats
    k_redgen<<<dim3(2,512), 256, 0, stream>>>(Pbig, PPa, 512, 12);
    k_redgen<<<dim3(2,32), 256, 0, stream>>>(PPa, PPb, 512, 16);
    k_redfin<<<1, 256, 0, stream>>>(PPb, 512, 32, 64, mean1, rs1);
    // y1 (pre-norm) stays in Za; norm1 fused into gemm2

    // ---- layer 2: 64 -> 64 ----
    k_gemm2<<<MTOT/64, 256, 0, stream>>>(Za, mean1, rs1, Bp2, Zb, Zc, Zd);
    k_prop<<<NNODES/8, 256, 0, stream>>>(rowptr, epk, Zd, Zc, 1.f, Zc, -2.f, nullptr);
    k_prop<<<NNODES/8, 256, 0, stream>>>(rowptr, epk, Zc, Zb, 1.f, Zb, -1.f, Pbig);      // y2 + stats
    k_redgen<<<dim3(2,512), 256, 0, stream>>>(Pbig, PPa, 512, 12);
    k_redgen<<<dim3(2,32), 256, 0, stream>>>(PPa, PPb, 512, 16);
    k_redfin<<<1, 256, 0, stream>>>(PPb, 512, 32, 64, mean2, rs2);
    k_normrelu<<<MTOT*64/2048, 256, 0, stream>>>(Zb, mean2, rs2, Za);                    // X3 = Za

    // ---- layer 3: 64 -> 256 (propagate in 64-dim input space) ----
    k_prop<<<NNODES/8, 256, 0, stream>>>(rowptr, epk, Za, (const ushort*)nullptr, 0.f, Zb, -1.f, nullptr); // T1 = -S(X3)
    k_prop<<<NNODES/8, 256, 0, stream>>>(rowptr, epk, Zb, Za, -1.f, Zc, -2.f, nullptr);                    // T2 = -X3 - 2S(T1)
    k_gemm3<<<MTOT/64, 256, 0, stream>>>(Za, Zb, Zc, Bp3, Ybf, Pst3);
    k_redgen<<<dim3(8,256), 256, 0, stream>>>(Pst3, PPa, 2048, 12);
    k_redgen<<<dim3(8,16), 256, 0, stream>>>(PPa, PPb, 2048, 16);
    k_redfin<<<4, 256, 0, stream>>>(PPb, 2048, 16, 256, mean3, rs3);
    k_final<<<MTOT/8, 256, 0, stream>>>(Ybf, x, mean3, rs3, (float*)d_out);
}